// Round 8
// baseline (248.889 us; speedup 1.0000x reference)
//
#include <hip/hip_runtime.h>

// Butterfly (untied, increasing stride), batch=32768, n=1024, m=10 stages, nstack=1.
//
// Round-8 = r7 (92us) + occupancy/latency fixes from its counters (VALUBusy
// 14.8%, Occ 18.6%: latency-exposed, LDS-capped at 12 waves/CU):
//  * ONE 32 KB LDS union, time-multiplexed: tblA (stages 0..3, phase 1) ->
//    wave-private transpose buffers (phase 2) -> tblF (stages 8,9, staged LATE
//    after the E->F transpose when buffers are dead). 48->32 KB lifts the
//    occupancy cap 12 -> 16 waves/CU (VGPR-capped now).
//  * x input loads issued BEFORE tblA staging: the pre-barrier vmcnt(0) drain
//    absorbs x-load + staging-gather latency together (MLP) instead of
//    serializing them per wave.
//  * Everything else identical to r7: shuffle-free 3-layout pipeline
//    A (0..3, LDS twiddles) -> transpose -> E (4..7, global 16-line gathers)
//    -> transpose -> F (8,9, LDS twiddles), dense float4 stores + bias.
// Fallbacks: r7 = 92us, r5 = 97us. Tripwire: WRITE_SIZE must stay 131072.

constexpr int N = 1024;
constexpr int B_ROWS = 4;   // rows per wave
constexpr int WAVES = 4;    // waves per block (block = 256 threads)
constexpr int WBUF  = 1344; // floats per wave transpose buffer (max idx 1323)

// Layout A: lane holds e = 16*lane + j (j=0..15). Stages 0..3. Twiddle from LDS.
template<int ST>
__device__ __forceinline__ void stageA(float (&v)[4][16],
                                       const float4* __restrict__ tbl, // LDS [512]
                                       const int lane)
{
    constexpr int s = 1 << ST;
    #pragma unroll
    for (int pi = 0; pi < 8; ++pi) {
        const int jl = ((pi >> ST) << (ST + 1)) | (pi & (s - 1));
        const int jh = jl + s;
        const float4 t = tbl[(pi << 6) | lane];
        #pragma unroll
        for (int r = 0; r < 4; ++r) {
            const float lo = v[r][jl], hi = v[r][jh];
            v[r][jl] = t.x * lo + t.y * hi;
            v[r][jh] = t.z * lo + t.w * hi;
        }
    }
}

// Layout E: lane (a=lane>>4, b=lane&15) holds e = 256*a + 16*k + b (k=0..15).
// Stages 4..7 (pair bit ST-4 of k). Twiddle from global (cheap 16-line gather).
template<int ST>
__device__ __forceinline__ void stageE(float (&v)[4][16],
                                       const float4* __restrict__ tw4,
                                       const int lane)
{
    constexpr int s  = 1 << ST;
    constexpr int km = 1 << (ST - 4);
    const int a = lane >> 4, b = lane & 15;
    #pragma unroll
    for (int pi = 0; pi < 8; ++pi) {
        const int kl = ((pi >> (ST - 4)) << (ST - 3)) | (pi & (km - 1));
        const int kh = kl + km;
        const int e  = 256 * a + 16 * kl + b;
        const int pr = ((e >> (ST + 1)) << ST) | (e & (s - 1));
        const float4 t = tw4[ST * 512 + pr];
        #pragma unroll
        for (int r = 0; r < 4; ++r) {
            const float lo = v[r][kl], hi = v[r][kh];
            v[r][kl] = t.x * lo + t.y * hi;
            v[r][kh] = t.z * lo + t.w * hi;
        }
    }
}

// Layout F: lane holds e = a*256 + 4*lane + b10, slot m = 4*a + b10.
// Stages 8,9 (pair bit ST-8 of a). Twiddle from LDS.
template<int ST>
__device__ __forceinline__ void stageF(float (&v)[4][16],
                                       const float4* __restrict__ tbl, // LDS [512]
                                       const int lane)
{
    constexpr int am = 1 << (ST - 8);
    #pragma unroll
    for (int pi = 0; pi < 8; ++pi) {
        const int ai   = pi >> 2;       // 0..1
        const int b10  = pi & 3;
        const int a_lo = ((ai >> (ST - 8)) << (ST - 7)) | (ai & (am - 1));
        const int a_hi = a_lo + am;
        const int ml   = a_lo * 4 + b10;
        const int mh   = a_hi * 4 + b10;
        const float4 t = tbl[(pi << 6) | lane];
        #pragma unroll
        for (int r = 0; r < 4; ++r) {
            const float lo = v[r][ml], hi = v[r][mh];
            v[r][ml] = t.x * lo + t.y * hi;
            v[r][mh] = t.z * lo + t.w * hi;
        }
    }
}

__global__ __launch_bounds__(256, 2)
void butterfly_kernel(const float* __restrict__ x,
                      const float* __restrict__ tw,    // [10][512][2][2]
                      const float* __restrict__ bias,  // [1024]
                      float* __restrict__ out)
{
    // 32 KB union, time-multiplexed across barrier-separated phases:
    //   phase 1: tblA[4][512] float4   (stages 0..3 twiddles)
    //   phase 2: per-wave transpose buffers (4 x 5.3 KB)
    //   phase 3: tblF[2][512] float4   (stages 8,9 twiddles, staged late)
    __shared__ __align__(16) float uni[8192];

    const int t    = threadIdx.x;
    const int lane = t & 63;
    const int g    = t >> 6;

    const float4* tw4 = (const float4*)tw;
    const size_t row0 = ((size_t)blockIdx.x * WAVES + g) * B_ROWS;

    float v[4][16];

    // ---- issue x loads FIRST (layout A: lane's 64B run per row) ----
    #pragma unroll
    for (int r = 0; r < 4; ++r) {
        const float* px = x + (row0 + r) * N + 16 * lane;
        #pragma unroll
        for (int i = 0; i < 4; ++i) {
            const float4 d = *(const float4*)(px + 4 * i);
            v[r][4 * i + 0] = d.x; v[r][4 * i + 1] = d.y;
            v[r][4 * i + 2] = d.z; v[r][4 * i + 3] = d.w;
        }
    }

    // ---- stage tblA (stages 0..3) while x loads are in flight ----
    {
        float4* tblA = (float4*)uni;                   // [4][512]
        #pragma unroll
        for (int st = 0; st < 4; ++st) {
            const int s = 1 << st;
            #pragma unroll
            for (int h = 0; h < 2; ++h) {
                const int idx = t + 256 * h;           // 0..511
                const int pi = idx >> 6, ln = idx & 63;
                const int jl = ((pi >> st) << (st + 1)) | (pi & (s - 1));
                const int e  = 16 * ln + jl;
                const int pr = ((e >> (st + 1)) << st) | (e & (s - 1));
                tblA[st * 512 + idx] = tw4[st * 512 + pr];
            }
        }
    }
    __syncthreads();   // barrier 1: tblA ready (drains x loads too)

    // ---- stages 0..3 (layout A, LDS twiddles) ----
    {
        const float4* tblA = (const float4*)uni;
        stageA<0>(v, tblA + 0 * 512, lane);
        stageA<1>(v, tblA + 1 * 512, lane);
        stageA<2>(v, tblA + 2 * 512, lane);
        stageA<3>(v, tblA + 3 * 512, lane);
    }
    __syncthreads();   // barrier 2: tblA dead -> buffers may overwrite

    float* wb = uni + g * WBUF;                        // wave-private 5.3 KB

    // ---- transpose A -> E ----
    // addr(e) = e + 4*(e>>4) + 16*((e>>8)&3). Write: e = 16*lane + j (contig 16).
    // Read: e = 256*a + 16*k + b -> addr = 336*a + 20*k + b.
    {
        const int wbase = 20 * lane + 16 * ((lane >> 4) & 3);
        const int a = lane >> 4, b = lane & 15;
        const int rb = 336 * a + b;
        #pragma unroll
        for (int r = 0; r < 4; ++r) {
            #pragma unroll
            for (int i = 0; i < 4; ++i)
                *(float4*)(wb + wbase + 4 * i) =
                    make_float4(v[r][4 * i + 0], v[r][4 * i + 1],
                                v[r][4 * i + 2], v[r][4 * i + 3]);
            #pragma unroll
            for (int k = 0; k < 16; ++k)
                v[r][k] = wb[rb + 20 * k];
        }
    }

    // ---- stages 4..7 (layout E, global twiddles: lane-consecutive low bits) ----
    stageE<4>(v, tw4, lane);
    stageE<5>(v, tw4, lane);
    stageE<6>(v, tw4, lane);
    stageE<7>(v, tw4, lane);

    // ---- transpose E -> F ----
    // u(e) = 256*e98 + 16*e30 + e74; addr2(u) = u + 4*(u>>4) + 16*((u>>8)&3).
    // Write (lane a,b holds k): addr2 = 336*a + 20*b + k (contig 16).
    // Read (lane L, slot m=4*aa+b10): addr2 = 336*aa + 80*(L&3) + 20*b10 + (L>>2).
    {
        const int a = lane >> 4, b = lane & 15;
        const int wbase = 336 * a + 20 * b;
        const int rb = 80 * (lane & 3) + (lane >> 2);
        #pragma unroll
        for (int r = 0; r < 4; ++r) {
            #pragma unroll
            for (int i = 0; i < 4; ++i)
                *(float4*)(wb + wbase + 4 * i) =
                    make_float4(v[r][4 * i + 0], v[r][4 * i + 1],
                                v[r][4 * i + 2], v[r][4 * i + 3]);
            #pragma unroll
            for (int m = 0; m < 16; ++m)
                v[r][m] = wb[rb + 336 * (m >> 2) + 20 * (m & 3)];
        }
    }

    __syncthreads();   // barrier 3: buffers dead -> tblF may overwrite

    // ---- stage tblF (stages 8,9) into the union (L2-warm gathers) ----
    {
        float4* tblF = (float4*)uni;                   // [2][512]
        #pragma unroll
        for (int f = 0; f < 2; ++f) {
            const int st = 8 + f;
            const int s  = 1 << st;
            const int am = 1 << (st - 8);
            #pragma unroll
            for (int h = 0; h < 2; ++h) {
                const int idx = t + 256 * h;
                const int pi = idx >> 6, ln = idx & 63;
                const int ai = pi >> 2, b10 = pi & 3;
                const int a_lo = ((ai >> (st - 8)) << (st - 7)) | (ai & (am - 1));
                const int e  = a_lo * 256 + 4 * ln + b10;
                const int pr = ((e >> (st + 1)) << st) | (e & (s - 1));
                tblF[f * 512 + idx] = tw4[st * 512 + pr];
            }
        }
    }
    __syncthreads();   // barrier 4: tblF ready

    // ---- stages 8,9 (layout F, LDS twiddles) ----
    {
        const float4* tblF = (const float4*)uni;
        stageF<8>(v, tblF + 0 * 512, lane);
        stageF<9>(v, tblF + 1 * 512, lane);
    }

    // ---- store with bias, layout F: dense float4 per 256-float block ----
    float4 bb[4];
    #pragma unroll
    for (int aa = 0; aa < 4; ++aa)
        bb[aa] = *(const float4*)(bias + aa * 256 + 4 * lane);
    #pragma unroll
    for (int r = 0; r < 4; ++r) {
        float* po = out + (row0 + r) * N + 4 * lane;
        #pragma unroll
        for (int aa = 0; aa < 4; ++aa) {
            float4 o;
            o.x = v[r][4 * aa + 0] + bb[aa].x;
            o.y = v[r][4 * aa + 1] + bb[aa].y;
            o.z = v[r][4 * aa + 2] + bb[aa].z;
            o.w = v[r][4 * aa + 3] + bb[aa].w;
            *(float4*)(po + aa * 256) = o;
        }
    }
}

extern "C" void kernel_launch(void* const* d_in, const int* in_sizes, int n_in,
                              void* d_out, int out_size, void* d_ws, size_t ws_size,
                              hipStream_t stream) {
    const float* x    = (const float*)d_in[0];   // [batch][1024]
    const float* tw   = (const float*)d_in[1];   // [1][10][512][2][2]
    const float* bias = (const float*)d_in[2];   // [1024]
    float* out        = (float*)d_out;

    const int batch  = in_sizes[0] / N;          // 32768
    const int blocks = batch / (B_ROWS * WAVES); // 2048
    hipLaunchKernelGGL(butterfly_kernel, dim3(blocks), dim3(256), 0, stream,
                       x, tw, bias, out);
}